// Round 6
// baseline (1954.247 us; speedup 1.0000x reference)
//
#include <hip/hip_runtime.h>

typedef __bf16 bf16x8 __attribute__((ext_vector_type(8)));
typedef float f32x4 __attribute__((ext_vector_type(4)));

__device__ __forceinline__ float sigmoidf_fast(float x) {
  return 1.f / (1.f + __expf(-x));
}
__device__ __forceinline__ float tanhf_fast(float x) {
  float e = __expf(2.f * x);
  return 1.f - 2.f / (e + 1.f);
}
__device__ __forceinline__ unsigned pack2(float a, float b) {
  unsigned short ua = __builtin_bit_cast(unsigned short, (__bf16)a);
  unsigned short ub = __builtin_bit_cast(unsigned short, (__bf16)b);
  return (unsigned)ua | ((unsigned)ub << 16);
}

// Fragment-major weight pack: Wt[(((tap*SLT + sl)*4 + q)*C4 + oc)*8 + j]
// = W[oc][ci][tap], ci = sl*32 + q*8 + j. A wave's 16-row x 16B A-fragment
// load is then fully-used 256B segments (coalesced global dwordx4).
__global__ void transpose_w_kernel(const float* __restrict__ Wsrc,
                                   __bf16* __restrict__ Wt, int C4, int C2) {
  int idx = blockIdx.x * 256 + threadIdx.x;
  int total = C4 * C2 * 9;
  if (idx >= total) return;
  int SLT = C2 >> 5;
  int j = idx & 7;
  int e = idx >> 3;
  int oc = e % C4; e /= C4;
  int q = e & 3;   e >>= 2;
  int sl = e % SLT;
  int tap = e / SLT;
  int ci = sl * 32 + q * 8 + j;
  Wt[idx] = (__bf16)Wsrc[(oc * C2 + ci) * 9 + tap];
}

// wbuf[t*8+b] = write-buffer parity of active step (read = 1-w); both
// buffers zero-init. wbuf[128+b] = final parity for the combine.
__global__ void build_wbuf_kernel(const int* __restrict__ mask,
                                  int* __restrict__ wbuf) {
  int b = threadIdx.x;  // 8 threads
  if (b >= 8) return;
  int m = 0;
  for (int t = 0; t < 16; ++t) {
    int w = 0;
    if (mask[t * 8 + b] > 0) { w = m & 1; ++m; }
    wbuf[t * 8 + b] = w;
  }
  wbuf[128 + b] = (m > 0) ? ((m - 1) & 1) : 0;
}

// out = (h[fin][dir0] + h[fin][dir1]) / 2, fin per batch
__global__ void combine_kernel(const float* __restrict__ h,
                               const int* __restrict__ fin,
                               float* __restrict__ out, int n, int chw,
                               size_t SZ) {
  int idx = blockIdx.x * 256 + threadIdx.x;
  if (idx >= n) return;
  int b = idx / chw;
  const float* hb = h + (size_t)fin[b] * 2 * SZ;
  out[idx] = (hb[idx] + hb[SZ + idx]) * 0.5f;
}

// LDS = image tile only (A goes global->VGPR directly; K-loop barrier-free)
// level-0: sT 6*66*136*2 = 107712   level-1: sT 6*34*264*2 = 107712
constexpr int SMEM_BYTES = 107712;

// Tile geometry (both levels OROWS=4, full M = 4C):
//  level-0: C=64,  M=256, N=256 (4 rows x 64): 4 M-waves x 2 N-groups
//  level-1: C=128, M=512, N=128 (4 rows x 32): 8 M-waves (no duplication)
// Per-wave acc 4 gates x 8 nt = 128 VGPR; per slice each wave does 32
// MFMAs on 4 A-frag global loads + 8 B ds_reads (2 half-N passes).
// K-loop: barrier-free, 1-slice-ahead register pipeline.
// NOTE: __launch_bounds__(512, 1) is required -- the (512,2) variant caps
// the allocator at 128 VGPRs (observed r0-r5) and this body needs ~220;
// LDS already limits us to 1 block/CU so the cap bought nothing but spill.
template <int C, int H, int W, int WAVES_M>
__device__ __forceinline__ void convlstm_block(
    char* smem, const float* __restrict__ x_t,
    const __bf16* __restrict__ Wt, const float* __restrict__ bias,
    const float* __restrict__ h_in, float* __restrict__ h_out,
    float* __restrict__ c_st, int d, int b, int y0)
{
  constexpr int Bz = 8, C2 = 2 * C, C4 = 4 * C;
  constexpr int OROWS = 4, IMR = OROWS + 2, COLS = W + 2;
  constexpr int C2p = C2 + 8;
  constexpr int PLANE = H * W, CHW = C * PLANE;
  constexpr int SLT = C2 / 32;            // 32-k slices per tap: 4 / 8
  constexpr int LSLT = (SLT == 4) ? 2 : 3;
  constexpr int NSL = 9 * SLT;            // 36 / 72 (even)
  constexpr int ASL = 32 * C4;            // A elements per slice
  constexpr int RG = 8 / WAVES_M;         // N-groups: 2 / 1
  constexpr int RPG = OROWS / RG;         // rows per group: 2 / 4
  constexpr int CTPR = W / 16;            // col-tiles per row: 4 / 2
  constexpr int IMG_ITERS = (C2 / 4) * IMR * W / 512;  // 24 both

  __bf16* sT = (__bf16*)smem;

  const int tid = threadIdx.x;
  const float* hin_b = h_in + (size_t)(d * Bz + b) * CHW;
  float* hout_b = h_out + (size_t)(d * Bz + b) * CHW;
  const __bf16* Wtd = Wt + (size_t)d * (9 * C4 * C2);

  const int lane = tid & 63, wv = tid >> 6;
  const int wvm = wv & (WAVES_M - 1);     // M-slice (16-ch group)
  const int rg = wv / WAVES_M;            // N-group (0 when WAVES_M=8)
  const int n = lane & 15, q = lane >> 4;

  // wave-sliced A base: oc = g*C + wvm*16 + n, k-slot q
  const __bf16* Ap = Wtd + (size_t)(q * C4 + wvm * 16 + n) * 8;

  uint4 A0[4], A1[4];
  auto loadA = [&](int sl, uint4 (&A)[4]) {
    const __bf16* p = Ap + (size_t)sl * ASL;
#pragma unroll
    for (int g = 0; g < 4; ++g)
      A[g] = *reinterpret_cast<const uint4*>(p + g * (C * 8));
  };

  // issue first two A slices before staging (lands under the stage)
  loadA(0, A0);
  loadA(1, A1);

  // ---- stage bf16([x | h]) window, transposed [row][slot][ci] ----
  const float* x_b = x_t + (size_t)b * CHW;
#pragma unroll
  for (int it = 0; it < IMG_ITERS; ++it) {
    int u = it * 512 + tid;
    int x = u % W;
    int t2 = u / W;
    int rr = t2 % IMR, ci4 = t2 / IMR;
    int yy = y0 + rr - 1;
    uint2 pv; pv.x = 0u; pv.y = 0u;
    if (yy >= 0 && yy < H) {
      int ci = ci4 * 4;
      const float* s0 = ((ci < C) ? (x_b + (size_t)ci * PLANE)
                                  : (hin_b + (size_t)(ci - C) * PLANE)) +
                        (size_t)yy * W + x;
      float f0 = s0[0];
      float f1 = s0[PLANE];
      float f2 = s0[2 * PLANE];
      float f3 = s0[3 * PLANE];
      pv.x = pack2(f0, f1);
      pv.y = pack2(f2, f3);
    }
    *reinterpret_cast<uint2*>(&sT[(rr * COLS + x + 1) * C2p + ci4 * 4]) = pv;
  }
  // x halo: slots 0 and W+1 zero
  for (int u = tid; u < (C2 / 4) * IMR * 2; u += 512) {
    int ci4 = u / (IMR * 2);
    int rem = u % (IMR * 2);
    int rr = rem >> 1;
    int slot = (rem & 1) ? (W + 1) : 0;
    uint2 z; z.x = 0u; z.y = 0u;
    *reinterpret_cast<uint2*>(&sT[(rr * COLS + slot) * C2p + ci4 * 4]) = z;
  }
  __syncthreads();

  f32x4 acc[4][8];
  f32x4 zero = {0.f, 0.f, 0.f, 0.f};
#pragma unroll
  for (int g = 0; g < 4; ++g)
#pragma unroll
    for (int nt = 0; nt < 8; ++nt) acc[g][nt] = zero;

  // B fragment load: half h covers nt = h*4 .. h*4+3
  auto loadB = [&](int sl, int h, bf16x8 (&Bv)[4]) {
    int tap = sl >> LSLT;
    int ci0 = (sl & (SLT - 1)) * 32;
    int ky = (tap * 11) >> 5;           // tap/3 for tap in [0,9)
    int kx = tap - 3 * ky;
#pragma unroll
    for (int j = 0; j < 4; ++j) {
      int nt = h * 4 + j;
      int row = rg * RPG + nt / CTPR + ky;
      int slot = (nt % CTPR) * 16 + n + kx;
      Bv[j] = *reinterpret_cast<const bf16x8*>(
          &sT[(row * COLS + slot) * C2p + ci0 + q * 8]);
    }
  };
  auto mfmaHalf = [&](uint4 (&A)[4], bf16x8 (&Bv)[4], int h) {
#pragma unroll
    for (int g = 0; g < 4; ++g) {
      bf16x8 a = __builtin_bit_cast(bf16x8, A[g]);
#pragma unroll
      for (int j = 0; j < 4; ++j)
        acc[g][h * 4 + j] = __builtin_amdgcn_mfma_f32_16x16x32_bf16(
            a, Bv[j], acc[g][h * 4 + j], 0, 0, 0);
    }
  };

  bf16x8 Bc[4], Bn[4];
  loadB(0, 0, Bc);
  for (int sl = 0; sl < NSL; sl += 2) {
    // slice sl uses A0
    loadB(sl, 1, Bn);
    mfmaHalf(A0, Bc, 0);
    loadB(sl + 1, 0, Bc);
    mfmaHalf(A0, Bn, 1);
    if (sl + 2 < NSL) loadA(sl + 2, A0);
    // slice sl+1 uses A1
    loadB(sl + 1, 1, Bn);
    mfmaHalf(A1, Bc, 0);
    if (sl + 2 < NSL) loadB(sl + 2, 0, Bc);
    mfmaHalf(A1, Bn, 1);
    if (sl + 3 < NSL) loadA(sl + 3, A1);
  }

  // ---- fused LSTM gate epilogue (D: col = n = px, row = q*4+r = channel) ----
  float* c_b = c_st + (size_t)(d * Bz + b) * CHW;
#pragma unroll
  for (int r = 0; r < 4; ++r) {
    const int cg = wvm * 16 + q * 4 + r;
    const float bi = bias[0 * C + cg];
    const float bff = bias[1 * C + cg];
    const float bo = bias[2 * C + cg];
    const float bg = bias[3 * C + cg];
#pragma unroll
    for (int nt = 0; nt < 8; ++nt) {
      const int y = y0 + rg * RPG + nt / CTPR;
      const int x = (nt % CTPR) * 16 + n;
      const size_t off = (size_t)cg * PLANE + (size_t)y * W + x;
      const float vi = acc[0][nt][r] + bi;
      const float vf = acc[1][nt][r] + bff;
      const float vo = acc[2][nt][r] + bo;
      const float vg = acc[3][nt][r] + bg;
      const float cn = sigmoidf_fast(vf) * c_b[off] + sigmoidf_fast(vi) * tanhf_fast(vg);
      c_b[off] = cn;
      hout_b[off] = sigmoidf_fast(vo) * tanhf_fast(cn);
    }
  }
}

// Persistent blocks (grid=256, one per CU) pop tiles 0..383 per step.
// [0,128) = level-1 (2 weight-units each, LPT first): d-major, 8 b x 8 yb;
// [128,384) = level-0 (1 unit): d-major, 8 b x 16 yb. At full activity:
// 512 units / 256 CUs = exactly 2 per CU via the queue.
// Masked (t,b) tiles are no-ops (h ping-pongs on active steps, c in place).
__global__ __launch_bounds__(512, 1)
void step_kernel(const float* __restrict__ x0, const float* __restrict__ x1,
                 const int* __restrict__ mask_t, const int* __restrict__ wbuf_t,
                 int* __restrict__ counter,
                 const __bf16* __restrict__ Wt0, const __bf16* __restrict__ Wt1,
                 const float* __restrict__ bf0, const float* __restrict__ bb0,
                 const float* __restrict__ bf1, const float* __restrict__ bb1,
                 float* __restrict__ h0, float* __restrict__ c0,
                 float* __restrict__ h1, float* __restrict__ c1)
{
  __shared__ __align__(16) char smem[SMEM_BYTES];
  __shared__ int s_pop;
  constexpr size_t SZ0 = (size_t)8 * 64 * 64 * 64;
  constexpr size_t SZ1 = (size_t)8 * 128 * 32 * 32;

  for (;;) {
    __syncthreads();                       // smem reuse + s_pop protection
    if (threadIdx.x == 0) s_pop = atomicAdd(counter, 1);
    __syncthreads();
    const int idx = s_pop;
    if (idx >= 384) return;

    if (idx < 128) {
      int d = idx >> 6;                    // d-major (weight L2 locality)
      int r = idx & 63;
      int b = r & 7, yb = r >> 3;          // yb in [0,8): 4 rows each
      if (mask_t[b] <= 0) continue;
      int w = wbuf_t[b];
      convlstm_block<128, 32, 32, 8>(smem, x1, Wt1,
          d == 0 ? bf1 : bb1,
          h1 + (size_t)(1 - w) * 2 * SZ1, h1 + (size_t)w * 2 * SZ1,
          c1, d, b, yb * 4);
    } else {
      int j = idx - 128;
      int d = j >> 7;                      // d-major
      int r = j & 127;
      int b = r & 7, yb = r >> 3;          // yb in [0,16): 4 rows each
      if (mask_t[b] <= 0) continue;
      int w = wbuf_t[b];
      convlstm_block<64, 64, 64, 4>(smem, x0, Wt0,
          d == 0 ? bf0 : bb0,
          h0 + (size_t)(1 - w) * 2 * SZ0, h0 + (size_t)w * 2 * SZ0,
          c0, d, b, yb * 4);
    }
  }
}

extern "C" void kernel_launch(void* const* d_in, const int* in_sizes, int n_in,
                              void* d_out, int out_size, void* d_ws, size_t ws_size,
                              hipStream_t stream) {
  const float* feat0 = (const float*)d_in[0];
  const float* feat1 = (const float*)d_in[1];
  const int* mask = (const int*)d_in[2];
  const float* Wf0 = (const float*)d_in[3];
  const float* bf0 = (const float*)d_in[4];
  const float* Wb0 = (const float*)d_in[5];
  const float* bb0 = (const float*)d_in[6];
  const float* Wf1 = (const float*)d_in[7];
  const float* bf1 = (const float*)d_in[8];
  const float* Wb1 = (const float*)d_in[9];
  const float* bb1 = (const float*)d_in[10];

  const int T = 16;
  const size_t SZ0 = (size_t)8 * 64 * 64 * 64;   // per-(dir,buf) h elems, level 0
  const size_t SZ1 = (size_t)8 * 128 * 32 * 32;  // level 1
  const size_t WT0 = (size_t)9 * 256 * 128;      // per-dir packed weights
  const size_t WT1 = (size_t)9 * 512 * 256;

  char* p = (char*)d_ws;
  __bf16* Wt0 = (__bf16*)p; p += 2 * WT0 * sizeof(__bf16);
  __bf16* Wt1 = (__bf16*)p; p += 2 * WT1 * sizeof(__bf16);
  float* h0 = (float*)p;    p += 4 * SZ0 * sizeof(float);   // [buf][dir][B][C][H][W]
  float* h1 = (float*)p;    p += 4 * SZ1 * sizeof(float);
  float* c0 = (float*)p;    p += 2 * SZ0 * sizeof(float);   // [dir][B][C][H][W]
  float* c1 = (float*)p;    p += 2 * SZ1 * sizeof(float);
  int* wbuf = (int*)p;      p += 256 * sizeof(int);         // [16][8] + fin[8]
  int* counters = (int*)p;  p += 16 * sizeof(int);

  hipMemsetAsync(h0, 0, 4 * SZ0 * sizeof(float), stream);
  hipMemsetAsync(h1, 0, 4 * SZ1 * sizeof(float), stream);
  hipMemsetAsync(c0, 0, 2 * SZ0 * sizeof(float), stream);
  hipMemsetAsync(c1, 0, 2 * SZ1 * sizeof(float), stream);
  hipMemsetAsync(counters, 0, 16 * sizeof(int), stream);

  transpose_w_kernel<<<((int)WT0 + 255) / 256, 256, 0, stream>>>(Wf0, Wt0, 256, 128);
  transpose_w_kernel<<<((int)WT0 + 255) / 256, 256, 0, stream>>>(Wb0, Wt0 + WT0, 256, 128);
  transpose_w_kernel<<<((int)WT1 + 255) / 256, 256, 0, stream>>>(Wf1, Wt1, 512, 256);
  transpose_w_kernel<<<((int)WT1 + 255) / 256, 256, 0, stream>>>(Wb1, Wt1 + WT1, 512, 256);
  build_wbuf_kernel<<<1, 8, 0, stream>>>(mask, wbuf);

  for (int t = 0; t < T; ++t) {
    step_kernel<<<256, 512, 0, stream>>>(
        feat0 + (size_t)t * SZ0, feat1 + (size_t)t * SZ1,
        mask + t * 8, wbuf + t * 8, counters + t,
        Wt0, Wt1, bf0, bb0, bf1, bb1,
        h0, c0, h1, c1);
  }

  float* out = (float*)d_out;
  combine_kernel<<<((int)SZ0 + 255) / 256, 256, 0, stream>>>(
      h0, wbuf + 128, out, (int)SZ0, 64 * 64 * 64, SZ0);
  combine_kernel<<<((int)SZ1 + 255) / 256, 256, 0, stream>>>(
      h1, wbuf + 128, out + SZ0, (int)SZ1, 128 * 32 * 32, SZ1);
}

// Round 7
// 1617.349 us; speedup vs baseline: 1.2083x; 1.2083x over previous
//
#include <hip/hip_runtime.h>

typedef __bf16 bf16x8 __attribute__((ext_vector_type(8)));
typedef float f32x4 __attribute__((ext_vector_type(4)));

__device__ __forceinline__ float sigmoidf_fast(float x) {
  return 1.f / (1.f + __expf(-x));
}
__device__ __forceinline__ float tanhf_fast(float x) {
  float e = __expf(2.f * x);
  return 1.f - 2.f / (e + 1.f);
}
__device__ __forceinline__ unsigned pack2(float a, float b) {
  unsigned short ua = __builtin_bit_cast(unsigned short, (__bf16)a);
  unsigned short ub = __builtin_bit_cast(unsigned short, (__bf16)b);
  return (unsigned)ua | ((unsigned)ub << 16);
}

// Gate-interleaved fragment-major pack:
//   Wt[(((tap*SLT + sl)*4 + q)*C4 + ch*4 + g)*8 + j] = W[g*C + ch][ci][tap]
// with ci = sl*32 + q*8 + j. A lane's 4 gate-fragments are contiguous 64B
// (imm offsets 0/16/32/48); 16 n-lanes form one dense 1KB segment.
__global__ void transpose_w_kernel(const float* __restrict__ Wsrc,
                                   __bf16* __restrict__ Wt, int C4, int C2) {
  int idx = blockIdx.x * 256 + threadIdx.x;
  int total = C4 * C2 * 9;
  if (idx >= total) return;
  int SLT = C2 >> 5;
  int j = idx & 7;
  int e = idx >> 3;
  int x = e % C4; e /= C4;     // x = ch*4 + g
  int q = e & 3;  e >>= 2;
  int sl = e % SLT;
  int tap = e / SLT;
  int g = x & 3, ch = x >> 2;
  int C = C4 >> 2;
  int oc = g * C + ch;
  int ci = sl * 32 + q * 8 + j;
  Wt[idx] = (__bf16)Wsrc[(oc * C2 + ci) * 9 + tap];
}

// wbuf[t*8+b] = write-buffer parity of active step (read = 1-w); both
// buffers zero-init. wbuf[128+b] = final parity for the combine.
__global__ void build_wbuf_kernel(const int* __restrict__ mask,
                                  int* __restrict__ wbuf) {
  int b = threadIdx.x;  // 8 threads
  if (b >= 8) return;
  int m = 0;
  for (int t = 0; t < 16; ++t) {
    int w = 0;
    if (mask[t * 8 + b] > 0) { w = m & 1; ++m; }
    wbuf[t * 8 + b] = w;
  }
  wbuf[128 + b] = (m > 0) ? ((m - 1) & 1) : 0;
}

// out = (h[fin][dir0] + h[fin][dir1]) / 2, fin per batch
__global__ void combine_kernel(const float* __restrict__ h,
                               const int* __restrict__ fin,
                               float* __restrict__ out, int n, int chw,
                               size_t SZ) {
  int idx = blockIdx.x * 256 + threadIdx.x;
  if (idx >= n) return;
  int b = idx / chw;
  const float* hb = h + (size_t)fin[b] * 2 * SZ;
  out[idx] = (hb[idx] + hb[SZ + idx]) * 0.5f;
}

// LDS = image tile only (A goes global->VGPR directly; K-loop barrier-free)
// level-0: sT 4*66*136*2 = 71808   level-1: sT 6*34*264*2 = 107712
constexpr int SMEM_BYTES = 107712;

// ===== round-4 geometry (proven 95us heavy step), K-loop de-VALU'd =====
// Tile = (dir d, 64-ch slice cs, batch b, OROWS rows): N = OROWS*W px,
// M = 256 oc (64 ch x 4 gates). 8 waves = 2 N-groups (rg) x 4 ch-waves
// (wvr). K-loop: tap-outer (9 rolled) x SLT-inner (unrolled): per slice
// 4 ds_read_b128 at imm offsets + 4 global dwordx4 off a running pointer
// + 16 MFMA. A register pipeline is 4 slices deep (A0..A3, s&3 static).
// Weight buffers are padded +4*ASL so tail prefetches need no guard.
template <int C, int H, int W, int OROWS>
__device__ __forceinline__ void convlstm_block(
    char* smem, const float* __restrict__ x_t,
    const __bf16* __restrict__ Wt, const float* __restrict__ bias,
    const float* __restrict__ h_in, float* __restrict__ h_out,
    float* __restrict__ c_st, int d, int b, int y0, int cs)
{
  constexpr int Bz = 8, C2 = 2 * C, C4 = 4 * C;
  constexpr int COLS = W + 2, C2p = C2 + 8, IMR = OROWS + 2;
  constexpr int PLANE = H * W, CHW = C * PLANE;
  constexpr int SLT = C2 / 32;            // 32-k slices per tap: 4 / 8
  constexpr int ASL = 32 * C4;            // A elements per slice
  constexpr int CTPR = (W / 16) < 4 ? (W / 16) : 4;
  constexpr int RPG = OROWS / 2;
  constexpr int IMG_ITERS = (C2 / 4) * IMR * W / 512;

  __bf16* sT = (__bf16*)smem;

  const int tid = threadIdx.x;
  const float* hin_b = h_in + (size_t)(d * Bz + b) * CHW;
  float* hout_b = h_out + (size_t)(d * Bz + b) * CHW;
  const __bf16* Wtd = Wt + (size_t)d * (9 * C4 * C2);

  const int lane = tid & 63, wv = tid >> 6;
  const int rg = wv >> 2, wvr = wv & 3;
  const int n = lane & 15, q = lane >> 4;

  // per-lane A base: ch = cs*64 + wvr*16 + n, gates contiguous at +8 elem
  const __bf16* Ap =
      Wtd + (size_t)((q * C4 + (cs * 64 + wvr * 16 + n) * 4) * 8);

  uint4 A0[4], A1[4], A2[4], A3[4];
  auto LD = [&](const __bf16* p, uint4 (&A)[4]) {
#pragma unroll
    for (int g = 0; g < 4; ++g)
      A[g] = *reinterpret_cast<const uint4*>(p + g * 8);
  };
  // prologue: 4 slices in flight before staging
  LD(Ap, A0);
  LD(Ap + ASL, A1);
  LD(Ap + 2 * (size_t)ASL, A2);
  LD(Ap + 3 * (size_t)ASL, A3);
  const __bf16* Arun = Ap + 4 * (size_t)ASL;

  // ---- stage bf16([x | h]) window, transposed [row][slot][ci] ----
  const float* x_b = x_t + (size_t)b * CHW;
#pragma unroll
  for (int it = 0; it < IMG_ITERS; ++it) {
    int u = it * 512 + tid;
    int x = u % W;
    int t2 = u / W;
    int rr = t2 % IMR, ci4 = t2 / IMR;
    int yy = y0 + rr - 1;
    uint2 pv; pv.x = 0u; pv.y = 0u;
    if (yy >= 0 && yy < H) {
      int ci = ci4 * 4;
      const float* s0 = ((ci < C) ? (x_b + (size_t)ci * PLANE)
                                  : (hin_b + (size_t)(ci - C) * PLANE)) +
                        (size_t)yy * W + x;
      float f0 = s0[0];
      float f1 = s0[PLANE];
      float f2 = s0[2 * PLANE];
      float f3 = s0[3 * PLANE];
      pv.x = pack2(f0, f1);
      pv.y = pack2(f2, f3);
    }
    *reinterpret_cast<uint2*>(&sT[(rr * COLS + x + 1) * C2p + ci4 * 4]) = pv;
  }
  // x halo: slots 0 and W+1 zero
  for (int u = tid; u < (C2 / 4) * IMR * 2; u += 512) {
    int ci4 = u / (IMR * 2);
    int rem = u % (IMR * 2);
    int rr = rem >> 1;
    int slot = (rem & 1) ? (W + 1) : 0;
    uint2 z; z.x = 0u; z.y = 0u;
    *reinterpret_cast<uint2*>(&sT[(rr * COLS + slot) * C2p + ci4 * 4]) = z;
  }
  __syncthreads();

  // per-nt B base pointers (computed once)
  const __bf16* Bb[4];
#pragma unroll
  for (int nt = 0; nt < 4; ++nt) {
    int row0 = rg * RPG + nt / CTPR;
    int slot0 = (nt % CTPR) * 16 + n;
    Bb[nt] = &sT[(row0 * COLS + slot0) * C2p + q * 8];
  }

  f32x4 acc[4][4];
  f32x4 zero = {0.f, 0.f, 0.f, 0.f};
#pragma unroll
  for (int g = 0; g < 4; ++g)
#pragma unroll
    for (int nt = 0; nt < 4; ++nt) acc[g][nt] = zero;

  for (int tap = 0; tap < 9; ++tap) {
    int ky = (tap * 11) >> 5;             // tap/3
    int kx = tap - 3 * ky;
    int toff = (ky * COLS + kx) * C2p;    // wave-uniform
    const __bf16* Bt0 = Bb[0] + toff;
    const __bf16* Bt1 = Bb[1] + toff;
    const __bf16* Bt2 = Bb[2] + toff;
    const __bf16* Bt3 = Bb[3] + toff;
#pragma unroll
    for (int s = 0; s < SLT; ++s) {
      bf16x8 b0 = *reinterpret_cast<const bf16x8*>(Bt0 + s * 32);
      bf16x8 b1 = *reinterpret_cast<const bf16x8*>(Bt1 + s * 32);
      bf16x8 b2 = *reinterpret_cast<const bf16x8*>(Bt2 + s * 32);
      bf16x8 b3 = *reinterpret_cast<const bf16x8*>(Bt3 + s * 32);
      uint4 (&Ac)[4] = (s & 3) == 0 ? A0
                     : (s & 3) == 1 ? A1
                     : (s & 3) == 2 ? A2 : A3;
#pragma unroll
      for (int g = 0; g < 4; ++g) {
        bf16x8 a = __builtin_bit_cast(bf16x8, Ac[g]);
        acc[g][0] = __builtin_amdgcn_mfma_f32_16x16x32_bf16(a, b0, acc[g][0], 0, 0, 0);
        acc[g][1] = __builtin_amdgcn_mfma_f32_16x16x32_bf16(a, b1, acc[g][1], 0, 0, 0);
        acc[g][2] = __builtin_amdgcn_mfma_f32_16x16x32_bf16(a, b2, acc[g][2], 0, 0, 0);
        acc[g][3] = __builtin_amdgcn_mfma_f32_16x16x32_bf16(a, b3, acc[g][3], 0, 0, 0);
      }
      // prefetch slice (tap*SLT + s + 4) into the buffer just consumed
      // (runs into the +4*ASL pad on the final slices -- loaded, unused)
      LD(Arun, Ac);
      Arun += ASL;
    }
  }

  // ---- fused LSTM gate epilogue (D: col = n = px, row = q*4+r = channel) ----
  float* c_b = c_st + (size_t)(d * Bz + b) * CHW;
#pragma unroll
  for (int r = 0; r < 4; ++r) {
    const int cg = cs * 64 + wvr * 16 + q * 4 + r;
    const float bi = bias[0 * C + cg];
    const float bff = bias[1 * C + cg];
    const float bo = bias[2 * C + cg];
    const float bg = bias[3 * C + cg];
#pragma unroll
    for (int nt = 0; nt < 4; ++nt) {
      const int y = y0 + rg * RPG + nt / CTPR;
      const int x = (nt % CTPR) * 16 + n;
      const size_t off = (size_t)cg * PLANE + (size_t)y * W + x;
      const float vi = acc[0][nt][r] + bi;
      const float vf = acc[1][nt][r] + bff;
      const float vo = acc[2][nt][r] + bo;
      const float vg = acc[3][nt][r] + bg;
      const float cn = sigmoidf_fast(vf) * c_b[off] + sigmoidf_fast(vi) * tanhf_fast(vg);
      c_b[off] = cn;
      hout_b[off] = sigmoidf_fast(vo) * tanhf_fast(cn);
    }
  }
}

// Persistent blocks (grid=256, one per CU) pop tiles 0..767 per step.
// [0,256) = level-1 ((d,cs)-major, 8 b x 8 yb, LPT first);
// [256,768) = level-0 (d-major, 8 b x 32 yb).
// Masked (t,b) tiles are no-ops (h ping-pongs on active steps, c in place).
__global__ __launch_bounds__(512, 2)
void step_kernel(const float* __restrict__ x0, const float* __restrict__ x1,
                 const int* __restrict__ mask_t, const int* __restrict__ wbuf_t,
                 int* __restrict__ counter,
                 const __bf16* __restrict__ Wt0, const __bf16* __restrict__ Wt1,
                 const float* __restrict__ bf0, const float* __restrict__ bb0,
                 const float* __restrict__ bf1, const float* __restrict__ bb1,
                 float* __restrict__ h0, float* __restrict__ c0,
                 float* __restrict__ h1, float* __restrict__ c1)
{
  __shared__ __align__(16) char smem[SMEM_BYTES];
  __shared__ int s_pop;
  constexpr size_t SZ0 = (size_t)8 * 64 * 64 * 64;
  constexpr size_t SZ1 = (size_t)8 * 128 * 32 * 32;

  for (;;) {
    __syncthreads();                       // smem reuse + s_pop protection
    if (threadIdx.x == 0) s_pop = atomicAdd(counter, 1);
    __syncthreads();
    const int idx = s_pop;
    if (idx >= 768) return;

    if (idx < 256) {
      int grp = idx >> 6;                  // (d,cs)-major
      int d = grp >> 1, cs = grp & 1;
      int r = idx & 63;
      int b = r & 7, yb = r >> 3;          // yb in [0,8): 4 rows each
      if (mask_t[b] <= 0) continue;
      int w = wbuf_t[b];
      convlstm_block<128, 32, 32, 4>(smem, x1, Wt1,
          d == 0 ? bf1 : bb1,
          h1 + (size_t)(1 - w) * 2 * SZ1, h1 + (size_t)w * 2 * SZ1,
          c1, d, b, yb * 4, cs);
    } else {
      int j = idx - 256;
      int d = j >> 8;                      // d-major
      int r = j & 255;
      int b = r & 7, yb = r >> 3;          // yb in [0,32): 2 rows each
      if (mask_t[b] <= 0) continue;
      int w = wbuf_t[b];
      convlstm_block<64, 64, 64, 2>(smem, x0, Wt0,
          d == 0 ? bf0 : bb0,
          h0 + (size_t)(1 - w) * 2 * SZ0, h0 + (size_t)w * 2 * SZ0,
          c0, d, b, yb * 2, 0);
    }
  }
}

extern "C" void kernel_launch(void* const* d_in, const int* in_sizes, int n_in,
                              void* d_out, int out_size, void* d_ws, size_t ws_size,
                              hipStream_t stream) {
  const float* feat0 = (const float*)d_in[0];
  const float* feat1 = (const float*)d_in[1];
  const int* mask = (const int*)d_in[2];
  const float* Wf0 = (const float*)d_in[3];
  const float* bf0 = (const float*)d_in[4];
  const float* Wb0 = (const float*)d_in[5];
  const float* bb0 = (const float*)d_in[6];
  const float* Wf1 = (const float*)d_in[7];
  const float* bf1 = (const float*)d_in[8];
  const float* Wb1 = (const float*)d_in[9];
  const float* bb1 = (const float*)d_in[10];

  const int T = 16;
  const size_t SZ0 = (size_t)8 * 64 * 64 * 64;   // per-(dir,buf) h elems, level 0
  const size_t SZ1 = (size_t)8 * 128 * 32 * 32;  // level 1
  const size_t WT0 = (size_t)9 * 256 * 128;      // per-dir packed weights
  const size_t WT1 = (size_t)9 * 512 * 256;
  const size_t APAD = (size_t)4 * 32 * 512;      // 4-slice prefetch overrun pad

  char* p = (char*)d_ws;
  __bf16* Wt0 = (__bf16*)p; p += 2 * WT0 * sizeof(__bf16);
  __bf16* Wt1 = (__bf16*)p; p += (2 * WT1 + APAD) * sizeof(__bf16);
  float* h0 = (float*)p;    p += 4 * SZ0 * sizeof(float);   // [buf][dir][B][C][H][W]
  float* h1 = (float*)p;    p += 4 * SZ1 * sizeof(float);
  float* c0 = (float*)p;    p += 2 * SZ0 * sizeof(float);   // [dir][B][C][H][W]
  float* c1 = (float*)p;    p += 2 * SZ1 * sizeof(float);
  int* wbuf = (int*)p;      p += 256 * sizeof(int);         // [16][8] + fin[8]
  int* counters = (int*)p;  p += 16 * sizeof(int);

  hipMemsetAsync(h0, 0, 4 * SZ0 * sizeof(float), stream);
  hipMemsetAsync(h1, 0, 4 * SZ1 * sizeof(float), stream);
  hipMemsetAsync(c0, 0, 2 * SZ0 * sizeof(float), stream);
  hipMemsetAsync(c1, 0, 2 * SZ1 * sizeof(float), stream);
  hipMemsetAsync(counters, 0, 16 * sizeof(int), stream);

  transpose_w_kernel<<<((int)WT0 + 255) / 256, 256, 0, stream>>>(Wf0, Wt0, 256, 128);
  transpose_w_kernel<<<((int)WT0 + 255) / 256, 256, 0, stream>>>(Wb0, Wt0 + WT0, 256, 128);
  transpose_w_kernel<<<((int)WT1 + 255) / 256, 256, 0, stream>>>(Wf1, Wt1, 512, 256);
  transpose_w_kernel<<<((int)WT1 + 255) / 256, 256, 0, stream>>>(Wb1, Wt1 + WT1, 512, 256);
  build_wbuf_kernel<<<1, 8, 0, stream>>>(mask, wbuf);

  for (int t = 0; t < T; ++t) {
    step_kernel<<<256, 512, 0, stream>>>(
        feat0 + (size_t)t * SZ0, feat1 + (size_t)t * SZ1,
        mask + t * 8, wbuf + t * 8, counters + t,
        Wt0, Wt1, bf0, bb0, bf1, bb1,
        h0, c0, h1, c1);
  }

  float* out = (float*)d_out;
  combine_kernel<<<((int)SZ0 + 255) / 256, 256, 0, stream>>>(
      h0, wbuf + 128, out, (int)SZ0, 64 * 64 * 64, SZ0);
  combine_kernel<<<((int)SZ1 + 255) / 256, 256, 0, stream>>>(
      h1, wbuf + 128, out + SZ0, (int)SZ1, 128 * 32 * 32, SZ1);
}